// Round 6
// baseline (4746.956 us; speedup 1.0000x reference)
//
#include <hip/hip_runtime.h>
#include <stdint.h>

// Problem constants
#define BB   128
#define DD   512
#define HH   1024
#define SS   512
#define G4   4096
#define KKT  48       // (D+H)/32 k-steps: kk 0..15 = x, 16..47 = h
#define NT_FC 64
#define KK_FC 32
#define USTRIDE 264   // fc kernel LDS stride

typedef __attribute__((ext_vector_type(8))) short short8v;
typedef __attribute__((ext_vector_type(4))) float float4v;

__device__ __forceinline__ unsigned short f2bf(float f) {
    union { float f; unsigned int u; } v; v.f = f;
    unsigned int u = v.u;
    unsigned int r = u + 0x7FFFu + ((u >> 16) & 1u);   // RNE
    return (unsigned short)(r >> 16);
}
__device__ __forceinline__ float sigm(float z) { return 1.f / (1.f + __expf(-z)); }
__device__ __forceinline__ float tanh_f(float z) { float e = __expf(2.f * z); return 1.f - 2.f / (e + 1.f); }

__device__ __forceinline__ short8v cvt8(const float4 f0, const float4 f1) {
    short8v o;
    o[0]=(short)f2bf(f0.x); o[1]=(short)f2bf(f0.y); o[2]=(short)f2bf(f0.z); o[3]=(short)f2bf(f0.w);
    o[4]=(short)f2bf(f1.x); o[5]=(short)f2bf(f1.y); o[6]=(short)f2bf(f1.z); o[7]=(short)f2bf(f1.w);
    return o;
}

// ---------------------------------------------------------------------------
// Pack W = [W_ih | W_hh] into bf16 MFMA fragment order, q-major n-tiles:
// ntile = q*64 + jseg  ->  W row = q*H + jseg*16 + (lane&15), k = kk*32+(lane>>4)*8
// ---------------------------------------------------------------------------
__global__ void pack_w_kernel(const float* __restrict__ W_ih,
                              const float* __restrict__ W_hh,
                              unsigned short* __restrict__ wp) {
    int idx = blockIdx.x * 256 + threadIdx.x;
    if (idx >= 256 * KKT * 64) return;
    int lane  = idx & 63;
    int kk    = (idx >> 6) % KKT;
    int ntile = idx / (64 * KKT);
    int q = ntile >> 6;
    int orow = q * HH + (ntile & 63) * 16 + (lane & 15);
    int kbase = kk * 32 + (lane >> 4) * 8;
    short8v ov;
#pragma unroll
    for (int i = 0; i < 8; ++i) {
        int k = kbase + i;
        float v = (k < DD) ? W_ih[(size_t)orow * DD + k]
                           : W_hh[(size_t)orow * HH + (k - DD)];
        ov[i] = (short)f2bf(v);
    }
    *(short8v*)&wp[(size_t)idx * 8] = ov;
}

__global__ void pack_fc_kernel(const float* __restrict__ fc_w,
                               unsigned short* __restrict__ wfc) {
    int idx = blockIdx.x * 256 + threadIdx.x;
    if (idx >= NT_FC * KK_FC * 64) return;
    int lane  = idx & 63;
    int kk    = (idx >> 6) % KK_FC;
    int ntile = idx / (64 * KK_FC);
    int o = ntile * 16 + (lane & 15);
    int kbase = kk * 32 + (lane >> 4) * 8;
    short8v ov;
#pragma unroll
    for (int i = 0; i < 8; ++i)
        ov[i] = (short)f2bf(fc_w[(size_t)o * HH + kbase + i]);
    *(short8v*)&wfc[(size_t)idx * 8] = ov;
}

// x -> bf16 MFMA A-fragment order: xpre[((mtile*S + t)*16 + kk)*64 + lane]
// mtile = batch/16 (= chain id in the persistent kernel)
__global__ void pack_x_kernel(const float* __restrict__ x,
                              unsigned short* __restrict__ xpre) {
    int idx = blockIdx.x * 256 + threadIdx.x;
    if (idx >= 8 * SS * 16 * 64) return;
    int lane  = idx & 63;
    int kk    = (idx >> 6) & 15;
    int t     = (idx >> 10) & (SS - 1);
    int mtile = idx >> 19;
    int b = mtile * 16 + (lane & 15);
    int d = kk * 32 + (lane >> 4) * 8;
    const float* src = &x[((size_t)b * SS + t) * DD + d];
    short8v ov;
#pragma unroll
    for (int i = 0; i < 8; ++i) ov[i] = (short)f2bf(src[i]);
    *(short8v*)&xpre[(size_t)idx * 8] = ov;
}

// zero h0 + barrier slots, pack bias bp[j*4+q] = b_ih[q*H+j] + b_hh[q*H+j]
__global__ void init_kernel(const float* __restrict__ b_ih,
                            const float* __restrict__ b_hh,
                            unsigned short* __restrict__ h0,
                            float* __restrict__ bpp,
                            unsigned int* __restrict__ bar) {
    int i = blockIdx.x * 256 + threadIdx.x;
    if (i < BB * HH) h0[i] = 0;
    if (i < G4) { int j = i >> 2, q = i & 3; bpp[i] = b_ih[q * HH + j] + b_hh[q * HH + j]; }
    if (i < 4096) bar[i] = 0;
}

// ---------------------------------------------------------------------------
// Persistent LSTM: 256 WGs = 8 chains (16 batch rows) x 32 WGs (32 j-units).
// Wave w = gate q; owns 2 n-tiles (u=0,1). All 96 W frags (384 VGPR) pinned
// resident. h + flags via RELAXED agent atomics (sc0/sc1, no cache inv).
// ---------------------------------------------------------------------------
template<int PRE>
__launch_bounds__(256, 1)
__global__ void lstm_persist(const float* __restrict__ x,
                             const unsigned short* __restrict__ xpre,
                             const unsigned short* __restrict__ wp,
                             const float* __restrict__ bp,
                             unsigned short* hbuf0,
                             unsigned short* hbuf1,
                             unsigned int* bar) {
    __shared__ __align__(16) unsigned short hl[32 * 64 * 8];   // 32 KiB h frags [kkh][lane]
    __shared__ __align__(16) float gl[16 * 132];               // 8.25 KiB gate exchange

    const int tid  = threadIdx.x;
    const int bid  = blockIdx.x;
    const int chain = bid >> 5;                 // 0..7 (16 batch rows each)
    const int jg    = bid & 31;                 // 0..31 (32 units each)
    const int lane = tid & 63;
    const int w    = tid >> 6;                  // wave = gate q
    const int l15  = lane & 15;
    const int lhi  = lane >> 4;

    // ---- resident W: 2 n-tiles x 48 kk = 384 VGPRs, loaded once, pinned ----
    short8v wr0[KKT], wr1[KKT];
    {
        const size_t nt0 = (size_t)(w * 64 + jg * 2 + 0) * KKT;
        const size_t nt1 = (size_t)(w * 64 + jg * 2 + 1) * KKT;
#pragma unroll
        for (int kk = 0; kk < KKT; ++kk) {
            wr0[kk] = *(const short8v*)&wp[((nt0 + kk) * 64 + lane) * 8];
            wr1[kk] = *(const short8v*)&wp[((nt1 + kk) * 64 + lane) * 8];
        }
    }
#pragma unroll
    for (int kk = 0; kk < KKT; ++kk) {
        asm volatile("" : "+v"(wr0[kk]));       // pin: non-rematerializable
        asm volatile("" : "+v"(wr1[kk]));
    }

    // ---- epilogue constants: thread owns (row erow, units eup, eup+1) ----
    const int erow = tid >> 4;                  // 0..15
    const int eup  = (tid & 15) * 2;            // 0..30 (local unit)
    const float4 eb0 = *(const float4*)&bp[(jg * 32 + eup) * 4];
    const float4 eb1 = *(const float4*)&bp[(jg * 32 + eup + 1) * 4];
    float ec0 = 0.f, ec1 = 0.f;

    // staging: thread loads row (tid>>4), 64 cols starting (tid&15)*64
    const int srow = tid >> 4;
    const int sseg = tid & 15;

#pragma unroll 1
    for (int t = 0; t < SS; ++t) {
        const unsigned short* hin = (t & 1) ? hbuf1 : hbuf0;
        unsigned short* hout      = (t & 1) ? hbuf0 : hbuf1;

        __syncthreads();                        // S2: prev-iter h stores acked by all

        // ---- arrive: publish "h(t-1) visible" ----
        if (t > 0 && tid == 0)
            __hip_atomic_store(&bar[chain * 32 + jg], (unsigned int)t,
                               __ATOMIC_RELAXED, __HIP_MEMORY_SCOPE_AGENT);

        float4v acc0 = {0.f, 0.f, 0.f, 0.f};
        float4v acc1 = {0.f, 0.f, 0.f, 0.f};

        // ---- x-phase (kk 0..15) — overlaps barrier latency ----
#pragma unroll
        for (int kq = 0; kq < 4; ++kq) {
#pragma unroll
            for (int kr = 0; kr < 4; ++kr) {
                const int kk = kq * 4 + kr;
                short8v a;
                if (PRE) {
                    a = *(const short8v*)&xpre[(((size_t)(chain * SS + t) * 16 + kk) * 64 + lane) * 8];
                } else {
                    const float* p = &x[((size_t)(chain * 16 + l15) * SS + t) * DD + kk * 32 + lhi * 8];
                    a = cvt8(*(const float4*)p, *(const float4*)(p + 4));
                }
                acc0 = __builtin_amdgcn_mfma_f32_16x16x32_bf16(a, wr0[kk], acc0, 0, 0, 0);
                acc1 = __builtin_amdgcn_mfma_f32_16x16x32_bf16(a, wr1[kk], acc1, 0, 0, 0);
            }
            __builtin_amdgcn_sched_barrier(0);  // cap prefetch register pressure
        }

        // ---- barrier wait: wave 0 polls the chain's 32 slots ----
        if (t > 0 && w == 0) {
            const unsigned int tgt = (unsigned int)t;
            for (;;) {
                unsigned int v = (lane < 32)
                    ? __hip_atomic_load(&bar[chain * 32 + lane],
                                        __ATOMIC_RELAXED, __HIP_MEMORY_SCOPE_AGENT)
                    : tgt;
                if (!__any(v < tgt)) break;
                __builtin_amdgcn_s_sleep(2);
            }
        }
        __syncthreads();                        // S3: h(t-1) globally visible
        __builtin_amdgcn_sched_barrier(0);

        // ---- stage h(t-1) -> hl frag-major (16 x u64 per thread) ----
        {
            const unsigned long long* hp = (const unsigned long long*)
                &hin[(size_t)(chain * 16 + srow) * HH + sseg * 64];
            unsigned long long hv8[16];
#pragma unroll
            for (int i = 0; i < 16; ++i)
                hv8[i] = __hip_atomic_load(hp + i, __ATOMIC_RELAXED, __HIP_MEMORY_SCOPE_AGENT);
            __builtin_amdgcn_sched_barrier(0);
#pragma unroll
            for (int i = 0; i < 16; ++i) {
                const int kkh = sseg * 2 + (i >> 3);
                const int lh  = (i >> 1) & 3;
                *(unsigned long long*)((char*)hl + kkh * 1024 + (lh * 16 + srow) * 16 + (i & 1) * 8) = hv8[i];
            }
        }
        __syncthreads();                        // S4: hl ready

        // ---- h-phase (kkh 0..31 == kk 16..47) ----
#pragma unroll
        for (int kq = 0; kq < 8; ++kq) {
#pragma unroll
            for (int kr = 0; kr < 4; ++kr) {
                const int kkh = kq * 4 + kr;
                short8v a = *(const short8v*)&hl[(size_t)(kkh * 64 + lane) * 8];
                acc0 = __builtin_amdgcn_mfma_f32_16x16x32_bf16(a, wr0[16 + kkh], acc0, 0, 0, 0);
                acc1 = __builtin_amdgcn_mfma_f32_16x16x32_bf16(a, wr1[16 + kkh], acc1, 0, 0, 0);
            }
            __builtin_amdgcn_sched_barrier(0);
        }

        // ---- gate exchange: gl[row][unit*4 + q] ----
#pragma unroll
        for (int r = 0; r < 4; ++r) {
            const int row = lhi * 4 + r;
            gl[row * 132 + (0 * 16 + l15) * 4 + w] = acc0[r];
            gl[row * 132 + (1 * 16 + l15) * 4 + w] = acc1[r];
        }
        __syncthreads();                        // S1: gates ready

        // ---- fused activation + state, h store (relaxed agent) + ack ----
        {
            float4 g0 = *(const float4*)&gl[erow * 132 + (eup + 0) * 4];
            float4 g1 = *(const float4*)&gl[erow * 132 + (eup + 1) * 4];
            float h0v, h1v;
            {
                float ig = sigm(g0.x + eb0.x), fg = sigm(g0.y + eb0.y);
                float gg = tanh_f(g0.z + eb0.z), og = sigm(g0.w + eb0.w);
                ec0 = fg * ec0 + ig * gg; h0v = og * tanh_f(ec0);
            }
            {
                float ig = sigm(g1.x + eb1.x), fg = sigm(g1.y + eb1.y);
                float gg = tanh_f(g1.z + eb1.z), og = sigm(g1.w + eb1.w);
                ec1 = fg * ec1 + ig * gg; h1v = og * tanh_f(ec1);
            }
            unsigned int hv = (unsigned int)f2bf(h0v) | ((unsigned int)f2bf(h1v) << 16);
            unsigned int* hp = (unsigned int*)&hout[(size_t)(chain * 16 + erow) * HH + jg * 32 + eup];
            __hip_atomic_store(hp, hv, __ATOMIC_RELAXED, __HIP_MEMORY_SCOPE_AGENT);
            __builtin_amdgcn_sched_barrier(0);
            asm volatile("s_waitcnt vmcnt(0)" ::: "memory");   // own store acked at MALL
            __builtin_amdgcn_sched_barrier(0);
        }
    }
}

// ---------------------------------------------------------------------------
// out[128,1024] = h_fin @ fc_w^T + fc_b  (fp32). 32 WGs: 2 Mg x 16 Ng.
// ---------------------------------------------------------------------------
__launch_bounds__(256)
__global__ void fc_kernel(const unsigned short* __restrict__ hfin,
                          const unsigned short* __restrict__ wfc,
                          const float* __restrict__ fc_b,
                          float* __restrict__ out) {
    __shared__ __align__(16) char smem[64 * USTRIDE * 2];
    unsigned short* ulds = (unsigned short*)smem;
    const int tid = threadIdx.x, bid = blockIdx.x;
    const int mg = bid >> 4;
    const int ng = bid & 15;
    const int m0 = mg * 64;
    const int lane = tid & 63, wave = tid >> 6;
    const int wm = wave >> 1, wn = wave & 1;

    float4v acc[2][2] = {};
    for (int cc = 0; cc < 4; ++cc) {
        __syncthreads();
        for (int it = 0; it < 16; ++it) {
            int v = tid + 256 * it;
            int row = v >> 6;
            int kl = (v & 63) * 4;
            ushort4 hv = *(const ushort4*)&hfin[(size_t)(m0 + row) * HH + cc * 256 + kl];
            *(ushort4*)&ulds[row * USTRIDE + kl] = hv;
        }
        __syncthreads();
#pragma unroll
        for (int kk = 0; kk < 8; ++kk) {
            int kkg = cc * 8 + kk;
            short8v a[2], b[2];
#pragma unroll
            for (int mtl = 0; mtl < 2; ++mtl) {
                int row = wm * 32 + mtl * 16 + (lane & 15);
                a[mtl] = *(const short8v*)&ulds[row * USTRIDE + kk * 32 + (lane >> 4) * 8];
            }
#pragma unroll
            for (int nt = 0; nt < 2; ++nt) {
                int ntile = ng * 4 + wn * 2 + nt;
                b[nt] = *(const short8v*)&wfc[(((size_t)ntile * KK_FC + kkg) * 64 + lane) * 8];
            }
#pragma unroll
            for (int mtl = 0; mtl < 2; ++mtl)
#pragma unroll
                for (int nt = 0; nt < 2; ++nt)
                    acc[mtl][nt] = __builtin_amdgcn_mfma_f32_16x16x32_bf16(
                        a[mtl], b[nt], acc[mtl][nt], 0, 0, 0);
        }
    }
#pragma unroll
    for (int mtl = 0; mtl < 2; ++mtl)
#pragma unroll
        for (int nt = 0; nt < 2; ++nt)
#pragma unroll
            for (int r = 0; r < 4; ++r) {
                int mrow = m0 + wm * 32 + mtl * 16 + (lane >> 4) * 4 + r;
                int o = ng * 64 + wn * 32 + nt * 16 + (lane & 15);
                out[(size_t)mrow * HH + o] = acc[mtl][nt][r] + fc_b[o];
            }
}

// ---------------------------------------------------------------------------
extern "C" void kernel_launch(void* const* d_in, const int* in_sizes, int n_in,
                              void* d_out, int out_size, void* d_ws, size_t ws_size,
                              hipStream_t stream) {
    const float* x    = (const float*)d_in[0];
    const float* W_ih = (const float*)d_in[1];
    const float* W_hh = (const float*)d_in[2];
    const float* b_ih = (const float*)d_in[3];
    const float* b_hh = (const float*)d_in[4];
    const float* fc_w = (const float*)d_in[5];
    const float* fc_b = (const float*)d_in[6];
    float* out = (float*)d_out;

    char* ws = (char*)d_ws;
    size_t off = 0;
    unsigned short* wp  = (unsigned short*)(ws + off); off += (size_t)256 * KKT * 64 * 8 * 2;     // 12 MB
    unsigned short* wfc = (unsigned short*)(ws + off); off += (size_t)NT_FC * KK_FC * 64 * 8 * 2; // 2 MB
    float* bp  = (float*)(ws + off); off += (size_t)G4 * 4;
    unsigned short* hbuf0 = (unsigned short*)(ws + off); off += (size_t)BB * HH * 2;
    unsigned short* hbuf1 = (unsigned short*)(ws + off); off += (size_t)BB * HH * 2;
    unsigned int* bar = (unsigned int*)(ws + off); off += 4096 * 4;
    size_t off_min = off;
    unsigned short* xpre = (unsigned short*)(ws + off);
    size_t off_full = off + (size_t)8 * SS * 16 * 64 * 8 * 2;                                     // +67 MB
    if (ws_size < off_min) return;
    const bool pre = (ws_size >= off_full);

    pack_w_kernel<<<3072, 256, 0, stream>>>(W_ih, W_hh, wp);
    pack_fc_kernel<<<512, 256, 0, stream>>>(fc_w, wfc);
    init_kernel<<<512, 256, 0, stream>>>(b_ih, b_hh, hbuf0, bp, bar);
    if (pre) {
        pack_x_kernel<<<16384, 256, 0, stream>>>(x, xpre);
        lstm_persist<1><<<256, 256, 0, stream>>>(x, xpre, wp, bp, hbuf0, hbuf1, bar);
    } else {
        lstm_persist<0><<<256, 256, 0, stream>>>(x, xpre, wp, bp, hbuf0, hbuf1, bar);
    }

    // S=512 even -> final h in hbuf0
    fc_kernel<<<32, 256, 0, stream>>>(hbuf0, wfc, fc_b, out);
}